// Round 1
// baseline (225.682 us; speedup 1.0000x reference)
//
#include <hip/hip_runtime.h>
#include <math.h>

// Problem constants (fixed by the reference harness).
constexpr int B = 16;
constexpr int N = 4096;
constexpr int K = 128;

// Each thread handles 4 consecutive k-elements of one (b, n) row.
// Streaming loads: int4 neighbors, float4 mask, 3x float4 cell_offsets,
// float4 store. Gathers (positions[b, j]) hit L1/L2 (48 KB/batch).
__global__ __launch_bounds__(256)
void pairwise_dist_kernel(const float* __restrict__ pos,
                          const int*   __restrict__ nbr,
                          const float* __restrict__ mask,
                          const float* __restrict__ cell,
                          const float* __restrict__ offs,
                          float*       __restrict__ out) {
    const int t = blockIdx.x * blockDim.x + threadIdx.x;
    const long long e0 = (long long)t * 4;          // first of 4 elements
    if (e0 >= (long long)B * N * K) return;

    const int row = (int)(e0 >> 7);                 // / K (K=128)
    const int b   = row >> 12;                      // / N (N=4096)
    const int n   = row & (N - 1);

    const float* __restrict__ pb = pos + (size_t)b * N * 3;
    const float xi = pb[n * 3 + 0];
    const float yi = pb[n * 3 + 1];
    const float zi = pb[n * 3 + 2];

    const float* __restrict__ cb = cell + b * 9;
    const float c00 = cb[0], c01 = cb[1], c02 = cb[2];
    const float c10 = cb[3], c11 = cb[4], c12 = cb[5];
    const float c20 = cb[6], c21 = cb[7], c22 = cb[8];

    const int4   jj = *(const int4*)  (nbr  + e0);
    const float4 mm = *(const float4*)(mask + e0);
    const float4 o0 = *(const float4*)(offs + e0 * 3);
    const float4 o1 = *(const float4*)(offs + e0 * 3 + 4);
    const float4 o2 = *(const float4*)(offs + e0 * 3 + 8);

    // Per-element (ox, oy, oz) unpack from the 12 packed floats.
    const float ox[4] = {o0.x, o0.w, o1.z, o2.y};
    const float oy[4] = {o0.y, o1.x, o1.w, o2.z};
    const float oz[4] = {o0.z, o1.y, o2.x, o2.w};
    const int   j [4] = {jj.x, jj.y, jj.z, jj.w};
    const float m [4] = {mm.x, mm.y, mm.z, mm.w};

    float res[4];
#pragma unroll
    for (int i = 0; i < 4; ++i) {
        const float* __restrict__ pj = pb + (size_t)j[i] * 3;
        const float dx = (pj[0] - xi) + ox[i] * c00 + oy[i] * c10 + oz[i] * c20;
        const float dy = (pj[1] - yi) + ox[i] * c01 + oy[i] * c11 + oz[i] * c21;
        const float dz = (pj[2] - zi) + ox[i] * c02 + oy[i] * c12 + oz[i] * c22;
        const float sq = dx * dx + dy * dy + dz * dz;
        res[i] = (m[i] > 0.0f) ? sqrtf(sq) : 0.0f;
    }

    *(float4*)(out + e0) = make_float4(res[0], res[1], res[2], res[3]);
}

extern "C" void kernel_launch(void* const* d_in, const int* in_sizes, int n_in,
                              void* d_out, int out_size, void* d_ws, size_t ws_size,
                              hipStream_t stream) {
    const float* positions     = (const float*)d_in[0]; // [B,N,3]
    const int*   neighbors     = (const int*)  d_in[1]; // [B,N,K]
    const float* neighbor_mask = (const float*)d_in[2]; // [B,N,K]
    const float* cell          = (const float*)d_in[3]; // [B,3,3]
    const float* cell_offsets  = (const float*)d_in[4]; // [B,N,K,3]
    float*       out           = (float*)d_out;         // [B,N,K]

    const long long total   = (long long)B * N * K;     // 8,388,608
    const int       threads = 256;
    const long long nthread = total / 4;                // 4 elems / thread
    const int       blocks  = (int)((nthread + threads - 1) / threads);

    pairwise_dist_kernel<<<blocks, threads, 0, stream>>>(
        positions, neighbors, neighbor_mask, cell, cell_offsets, out);
}

// Round 2
// 214.450 us; speedup vs baseline: 1.0524x; 1.0524x over previous
//
#include <hip/hip_runtime.h>
#include <math.h>

// Problem constants (fixed by the reference harness).
constexpr int B = 16;
constexpr int N = 4096;
constexpr int K = 128;

constexpr int ROWS_PER_BLOCK = 64;   // 64 rows x K=128 -> 8192 elems/block
constexpr int THREADS = 1024;        // 8 elems/thread (two float4 chunks)

// Stage the whole batch's positions (N atoms) in LDS as (x,y,z,pad) float4
// so each neighbor gather is a single ds_read_b128 instead of 3 divergent
// global dword loads. 64 KB LDS -> 2 blocks/CU -> 32 waves (full occupancy).
__global__ __launch_bounds__(THREADS)
void pairwise_dist_lds(const float* __restrict__ pos,
                       const int*   __restrict__ nbr,
                       const float* __restrict__ mask,
                       const float* __restrict__ cell,
                       const float* __restrict__ offs,
                       float*       __restrict__ out) {
    __shared__ float4 spos[N];       // 64 KB

    const int tid   = threadIdx.x;
    const int b     = blockIdx.x >> 6;   // 64 blocks per batch
    const int rblk  = blockIdx.x & 63;
    const int nbase = rblk * ROWS_PER_BLOCK;

    // --- Stage positions: 1024 threads x 12 consecutive floats (3x float4),
    // repacked into 4 padded float4 atoms each. Coalesced; L2-resident.
    {
        const float4* __restrict__ pb4 =
            (const float4*)(pos + (size_t)b * N * 3);
        const float4 r0 = pb4[tid * 3 + 0];
        const float4 r1 = pb4[tid * 3 + 1];
        const float4 r2 = pb4[tid * 3 + 2];
        const int a0 = tid * 4;
        spos[a0 + 0] = make_float4(r0.x, r0.y, r0.z, 0.f);
        spos[a0 + 1] = make_float4(r0.w, r1.x, r1.y, 0.f);
        spos[a0 + 2] = make_float4(r1.z, r1.w, r2.x, 0.f);
        spos[a0 + 3] = make_float4(r2.y, r2.z, r2.w, 0.f);
    }

    // Cell matrix: uniform per block -> scalar loads.
    const float* __restrict__ cb = cell + b * 9;
    const float c00 = cb[0], c01 = cb[1], c02 = cb[2];
    const float c10 = cb[3], c11 = cb[4], c12 = cb[5];
    const float c20 = cb[6], c21 = cb[7], c22 = cb[8];

    __syncthreads();

    const size_t blockElemBase = ((size_t)b * N + nbase) * K;

#pragma unroll
    for (int it = 0; it < 2; ++it) {
        const int    eLocal = it * 4096 + tid * 4;    // 4 consecutive elems
        const size_t e0     = blockElemBase + eLocal;
        const int    n      = nbase + (eLocal >> 7);  // row (K=128)

        const float4 pi = spos[n];   // broadcast within each row's lanes

        const int4   jj = *(const int4*)  (nbr  + e0);
        const float4 mm = *(const float4*)(mask + e0);
        const float4 o0 = *(const float4*)(offs + e0 * 3);
        const float4 o1 = *(const float4*)(offs + e0 * 3 + 4);
        const float4 o2 = *(const float4*)(offs + e0 * 3 + 8);

        const float ox[4] = {o0.x, o0.w, o1.z, o2.y};
        const float oy[4] = {o0.y, o1.x, o1.w, o2.z};
        const float oz[4] = {o0.z, o1.y, o2.x, o2.w};
        const int   j [4] = {jj.x, jj.y, jj.z, jj.w};
        const float m [4] = {mm.x, mm.y, mm.z, mm.w};

        float res[4];
#pragma unroll
        for (int i = 0; i < 4; ++i) {
            const float4 pj = spos[j[i]];            // one ds_read_b128
            const float dx = (pj.x - pi.x) + ox[i] * c00 + oy[i] * c10 + oz[i] * c20;
            const float dy = (pj.y - pi.y) + ox[i] * c01 + oy[i] * c11 + oz[i] * c21;
            const float dz = (pj.z - pi.z) + ox[i] * c02 + oy[i] * c12 + oz[i] * c22;
            const float sq = dx * dx + dy * dy + dz * dz;
            res[i] = (m[i] > 0.0f) ? sqrtf(sq) : 0.0f;
        }

        *(float4*)(out + e0) = make_float4(res[0], res[1], res[2], res[3]);
    }
}

extern "C" void kernel_launch(void* const* d_in, const int* in_sizes, int n_in,
                              void* d_out, int out_size, void* d_ws, size_t ws_size,
                              hipStream_t stream) {
    const float* positions     = (const float*)d_in[0]; // [B,N,3]
    const int*   neighbors     = (const int*)  d_in[1]; // [B,N,K]
    const float* neighbor_mask = (const float*)d_in[2]; // [B,N,K]
    const float* cell          = (const float*)d_in[3]; // [B,3,3]
    const float* cell_offsets  = (const float*)d_in[4]; // [B,N,K,3]
    float*       out           = (float*)d_out;         // [B,N,K]

    const int blocks = B * (N / ROWS_PER_BLOCK);        // 16 * 64 = 1024

    pairwise_dist_lds<<<blocks, THREADS, 0, stream>>>(
        positions, neighbors, neighbor_mask, cell, cell_offsets, out);
}